// Round 8
// baseline (157.522 us; speedup 1.0000x reference)
//
#include <hip/hip_runtime.h>

#define IMG_H 512
#define IMG_W 512
#define TW 64    // tile width
#define TH 32    // tile height (2 tiles per block, stacked in y)
#define GH 38    // gray rows staged per tile (TH + 6 halo)
#define AS 72    // gray LDS stride (floats)
#define VS 72    // V1/V2 LDS stride (floats)

__device__ __forceinline__ int reflect(int i, int n) {
    i = (i < 0) ? -i : i;
    return (i >= n) ? (2 * n - 2 - i) : i;
}
__device__ __forceinline__ float4 ld4s(const float* p) { return *(const float4*)p; }

struct RGB9 { float4 a0,a1,a2,b0,b1,b2,c0,c1,c2; };

__device__ __forceinline__ const float* rgbptr(const float* img, int by0, int i, int gx0, int j) {
    const int gy = reflect(by0 - 3 + i, IMG_H);
    return img + (size_t)gy * (IMG_W * 3) + (gx0 + 4 * j) * 3;
}

// D = valid float4-groups per row (18 interior, 17 edge), GO = group offset, N = D*38
template<int D, int GO, int N>
__device__ __forceinline__ void issue_loads(const float* img, int by0, int gx0, int tid, RGB9& r) {
    const int i0 = tid / D,         j0 = tid % D + GO;
    const int i1 = (tid+256) / D,   j1 = (tid+256) % D + GO;
    int idx2 = tid + 512; if (idx2 >= N) idx2 = N - 1;
    const int i2 = idx2 / D,        j2 = idx2 % D + GO;
    const float* p0 = rgbptr(img, by0, i0, gx0, j0);
    const float* p1 = rgbptr(img, by0, i1, gx0, j1);
    const float* p2 = rgbptr(img, by0, i2, gx0, j2);
    r.a0 = ld4s(p0); r.a1 = ld4s(p0+4); r.a2 = ld4s(p0+8);
    r.b0 = ld4s(p1); r.b1 = ld4s(p1+4); r.b2 = ld4s(p1+8);
    r.c0 = ld4s(p2); r.c1 = ld4s(p2+4); r.c2 = ld4s(p2+8);
}

#define GRAY4F(v0, v1, v2, dst) do { \
    float4 g_; \
    g_.x = (v0).x * 0.2989f + (v0).y * 0.5870f + (v0).z * 0.1140f; \
    g_.y = (v0).w * 0.2989f + (v1).x * 0.5870f + (v1).y * 0.1140f; \
    g_.z = (v1).z * 0.2989f + (v1).w * 0.5870f + (v2).x * 0.1140f; \
    g_.w = (v2).y * 0.2989f + (v2).z * 0.5870f + (v2).w * 0.1140f; \
    *(float4*)(dst) = g_; \
} while (0)

template<int D, int GO, int N>
__device__ __forceinline__ void gray_store(float* A, const RGB9& r, int tid) {
    {
        const int i = tid / D, j = tid % D + GO;
        GRAY4F(r.a0, r.a1, r.a2, &A[i * AS + 4 * j]);
    }
    {
        const int i = (tid+256) / D, j = (tid+256) % D + GO;
        GRAY4F(r.b0, r.b1, r.b2, &A[i * AS + 4 * j]);
    }
    if (tid + 512 < N) {
        const int i = (tid+512) / D, j = (tid+512) % D + GO;
        GRAY4F(r.c0, r.c1, r.c2, &A[i * AS + 4 * j]);
    }
}

// vertical composed 7-taps, rolling 2 output rows per item (8 reads / 2 rows)
template<int BMODE>  // 0 interior, 1 left, 2 right
__device__ __forceinline__ void vtaps(const float* A, float* B1, float* B2, int tid) {
    const float C1[7] = { 0.12007838f, 0.47403752f, 0.87992161f, 1.05192494f,
                          0.87992161f, 0.47403752f, 0.12007838f };
    const float C2[7] = { -0.12007838f, -0.23388076f, -0.17200333f, 0.0f,
                           0.17200333f,  0.23388076f,  0.12007838f };
    #pragma unroll
    for (int s = 0; s < 2; ++s) {
        if (s == 1 && tid >= 32) break;   // 288 items total
        const int idx = tid + 256 * s;
        const int rq = idx / 18, g = idx % 18;
        const bool bnd = (BMODE == 1 && g == 0) || (BMODE == 2 && g == 17);
        float p1[2][4] = {{0,0,0,0},{0,0,0,0}};
        float p2[2][4] = {{0,0,0,0},{0,0,0,0}};
        #pragma unroll
        for (int k = 0; k < 8; ++k) {
            const int row = 2 * rq + k;
            float x[4];
            if (!bnd) {
                const float4 q = ld4s(&A[row * AS + 4 * g]);
                x[0]=q.x; x[1]=q.y; x[2]=q.z; x[3]=q.w;
            } else if (BMODE == 1) {   // cols 0..3 <- reflected cols 8,7,6,5
                x[0]=A[row*AS+8]; x[1]=A[row*AS+7]; x[2]=A[row*AS+6]; x[3]=A[row*AS+5];
            } else {                   // cols 68..71 <- reflected cols 66,65,64,63
                x[0]=A[row*AS+66]; x[1]=A[row*AS+65]; x[2]=A[row*AS+64]; x[3]=A[row*AS+63];
            }
            if (k < 7) {
                #pragma unroll
                for (int c = 0; c < 4; ++c) {
                    p1[0][c] = fmaf(C1[k], x[c], p1[0][c]);
                    if (k != 3) p2[0][c] = fmaf(C2[k], x[c], p2[0][c]);
                }
            }
            if (k > 0) {
                #pragma unroll
                for (int c = 0; c < 4; ++c) {
                    p1[1][c] = fmaf(C1[k-1], x[c], p1[1][c]);
                    if (k != 4) p2[1][c] = fmaf(C2[k-1], x[c], p2[1][c]);
                }
            }
        }
        #pragma unroll
        for (int o = 0; o < 2; ++o) {
            float4 w1, w2;
            w1.x=p1[o][0]; w1.y=p1[o][1]; w1.z=p1[o][2]; w1.w=p1[o][3];
            w2.x=p2[o][0]; w2.y=p2[o][1]; w2.z=p2[o][2]; w2.w=p2[o][3];
            *(float4*)&B1[(2*rq+o)*VS + 4*g] = w1;
            *(float4*)&B2[(2*rq+o)*VS + 4*g] = w2;
        }
    }
}

__device__ __forceinline__ void htaps_store(const float* B1, const float* B2,
                                            float* outB, int by0, int bx0, int tid) {
    const float a1 = 0.17200333f, a2 = 0.23388076f, a3 = 0.12007838f;
    const float c0 = 1.05192494f, c1 = 0.87992161f, c2 = 0.47403752f, c3 = 0.12007838f;
    #pragma unroll
    for (int t = 0; t < 2; ++t) {
        const int idx = tid + 256 * t;
        const int r = idx >> 4, g = idx & 15;
        const float* q1 = &B1[r * VS + 4 * g];
        const float* q2 = &B2[r * VS + 4 * g];
        float u[12], w[12];
        float4 v;
        v = ld4s(q1);    u[0]=v.x; u[1]=v.y; u[2]=v.z; u[3]=v.w;
        v = ld4s(q1+4);  u[4]=v.x; u[5]=v.y; u[6]=v.z; u[7]=v.w;
        v = ld4s(q1+8);  u[8]=v.x; u[9]=v.y; u[10]=v.z; u[11]=v.w;
        v = ld4s(q2);    w[0]=v.x; w[1]=v.y; w[2]=v.z; w[3]=v.w;
        v = ld4s(q2+4);  w[4]=v.x; w[5]=v.y; w[6]=v.z; w[7]=v.w;
        v = ld4s(q2+8);  w[8]=v.x; w[9]=v.y; w[10]=v.z; w[11]=v.w;
        float res[4];
        #pragma unroll
        for (int p = 0; p < 4; ++p) {
            const int j = p + 4;
            const float sx = (u[j+3]-u[j-3])*a3 + (u[j+2]-u[j-2])*a2 + (u[j+1]-u[j-1])*a1;
            const float sy = c0*w[j] + c1*(w[j-1]+w[j+1]) + c2*(w[j-2]+w[j+2]) + c3*(w[j-3]+w[j+3]);
            res[p] = (sx*sx + sy*sy > 900.0f) ? 1.0f : 0.0f;
        }
        float4 rv; rv.x=res[0]; rv.y=res[1]; rv.z=res[2]; rv.w=res[3];
        *(float4*)&outB[(size_t)(by0 + r) * IMG_W + bx0 + 4*g] = rv;
    }
}

template<int D, int GO, int N, int BMODE>
__device__ __forceinline__ void run_block(const float* img, float* outB,
                                          int bx0, int byB, int tid,
                                          float* A, float* B1, float* B2) {
    const int gx0 = bx0 - 4;
    RGB9 rA, rB;
    issue_loads<D,GO,N>(img, byB, gx0, tid, rA);          // tile 0 loads
    gray_store<D,GO,N>(A, rA, tid);                       // P0: gray0
    __syncthreads();
    issue_loads<D,GO,N>(img, byB + TH, gx0, tid, rB);     // tile 1 loads in flight
    vtaps<BMODE>(A, B1, B2, tid);                         // P1: vtaps0
    __syncthreads();
    htaps_store(B1, B2, outB, byB, bx0, tid);             // P2: htaps0 + store0
    gray_store<D,GO,N>(A, rB, tid);                       //     + gray1 (waits vmcnt here)
    __syncthreads();
    vtaps<BMODE>(A, B1, B2, tid);                         // P3: vtaps1
    __syncthreads();
    htaps_store(B1, B2, outB, byB + TH, bx0, tid);        // P4: htaps1 + store1
}

__global__ __launch_bounds__(256, 4)
void edge_fused_kernel(const float* __restrict__ in, float* __restrict__ out) {
    const int bx0 = blockIdx.x * TW;
    const int byB = blockIdx.y * (2 * TH);
    const int b   = blockIdx.z;
    const int tid = threadIdx.x;
    __shared__ float A[GH * AS];    // 10.9 KB
    __shared__ float B1[TH * VS];   //  9.2 KB
    __shared__ float B2[TH * VS];   //  9.2 KB
    const float* img = in + (size_t)b * (IMG_H * IMG_W * 3);
    float* outB = out + (size_t)b * (IMG_H * IMG_W);
    if (bx0 == 0)                    run_block<17,1,646,1>(img, outB, bx0, byB, tid, A, B1, B2);
    else if (bx0 + TW == IMG_W)      run_block<17,0,646,2>(img, outB, bx0, byB, tid, A, B1, B2);
    else                             run_block<18,0,684,0>(img, outB, bx0, byB, tid, A, B1, B2);
}

extern "C" void kernel_launch(void* const* d_in, const int* in_sizes, int n_in,
                              void* d_out, int out_size, void* d_ws, size_t ws_size,
                              hipStream_t stream) {
    const float* in = (const float*)d_in[0];
    float* out = (float*)d_out;
    const int B = in_sizes[0] / (IMG_H * IMG_W * 3);
    dim3 grid(IMG_W / TW, IMG_H / (2 * TH), B);
    dim3 block(256, 1, 1);
    edge_fused_kernel<<<grid, block, 0, stream>>>(in, out);
}